// Round 1
// baseline (5328.464 us; speedup 1.0000x reference)
//
#include <hip/hip_runtime.h>

// LightGCN: final = (ego + A·ego + A²·ego + A³·ego) / 4
// ego = concat(user_emb, item_emb)  [N, 64] f32
// A given as COO (rows, cols, vals), E = 2,000,000.

#define NUM_USERS 100000
#define NUM_ITEMS 200000
#define NN (NUM_USERS + NUM_ITEMS)
#define DIM 64

// ---------------- init: ego -> out (acc), hA (h0); zero hB ----------------
__global__ void init_kernel(const float4* __restrict__ user4,
                            const float4* __restrict__ item4,
                            float4* __restrict__ out4,
                            float4* __restrict__ hA4,
                            float4* __restrict__ hB4,
                            int total4, int user4n) {
    int i = blockIdx.x * blockDim.x + threadIdx.x;
    if (i >= total4) return;
    float4 v = (i < user4n) ? user4[i] : item4[i - user4n];
    out4[i] = v;
    hA4[i]  = v;
    hB4[i]  = make_float4(0.f, 0.f, 0.f, 0.f);
}

// ---------------- scatter SpMM: y[row] += val * x[col] --------------------
// 16 threads per edge; each thread handles 4 consecutive floats of D=64.
__global__ void spmm_atomic(const int* __restrict__ rows,
                            const int* __restrict__ cols,
                            const float* __restrict__ vals,
                            const float* __restrict__ x,
                            float* __restrict__ y,
                            int nedges) {
    long long t = (long long)blockIdx.x * blockDim.x + threadIdx.x;
    if (t >= (long long)nedges * 16) return;
    int e = (int)(t >> 4);
    int c = ((int)t & 15) << 2;       // 0,4,8,...,60
    int row = rows[e];
    int col = cols[e];
    float v  = vals[e];
    const float4 xv = *(const float4*)(x + (long long)col * DIM + c);
    float* yp = y + (long long)row * DIM + c;
    atomicAdd(yp + 0, v * xv.x);
    atomicAdd(yp + 1, v * xv.y);
    atomicAdd(yp + 2, v * xv.z);
    atomicAdd(yp + 3, v * xv.w);
}

// ---------------- acc: out += h; zero the other ping-pong buffer ----------
__global__ void acc_kernel(float4* __restrict__ out4,
                           const float4* __restrict__ h4,
                           float4* __restrict__ zero4,
                           int total4) {
    int i = blockIdx.x * blockDim.x + threadIdx.x;
    if (i >= total4) return;
    float4 o = out4[i];
    float4 h = h4[i];
    o.x += h.x; o.y += h.y; o.z += h.z; o.w += h.w;
    out4[i] = o;
    zero4[i] = make_float4(0.f, 0.f, 0.f, 0.f);
}

// ---------------- final: out = (out + h) * 0.25 ---------------------------
__global__ void final_kernel(float4* __restrict__ out4,
                             const float4* __restrict__ h4,
                             int total4) {
    int i = blockIdx.x * blockDim.x + threadIdx.x;
    if (i >= total4) return;
    float4 o = out4[i];
    float4 h = h4[i];
    o.x = (o.x + h.x) * 0.25f;
    o.y = (o.y + h.y) * 0.25f;
    o.z = (o.z + h.z) * 0.25f;
    o.w = (o.w + h.w) * 0.25f;
    out4[i] = o;
}

extern "C" void kernel_launch(void* const* d_in, const int* in_sizes, int n_in,
                              void* d_out, int out_size, void* d_ws, size_t ws_size,
                              hipStream_t stream) {
    const float* user_emb = (const float*)d_in[0];
    const float* item_emb = (const float*)d_in[1];
    const int*   adj_rows = (const int*)d_in[2];
    const int*   adj_cols = (const int*)d_in[3];
    const float* adj_vals = (const float*)d_in[4];
    float* out = (float*)d_out;

    const int E = in_sizes[2];
    const long long total = (long long)NN * DIM;      // 19.2M
    const int total4 = (int)(total / 4);              // 4.8M
    const int user4n = NUM_USERS * DIM / 4;           // 1.6M

    float* hA = (float*)d_ws;                          // N*D floats
    float* hB = hA + total;                            // N*D floats

    const int TB = 256;
    const int gridEW = (int)(((long long)E * 16 + TB - 1) / TB);
    const int gridV  = (total4 + TB - 1) / TB;

    // acc = ego; hA = ego; hB = 0
    init_kernel<<<gridV, TB, 0, stream>>>((const float4*)user_emb,
                                          (const float4*)item_emb,
                                          (float4*)out, (float4*)hA, (float4*)hB,
                                          total4, user4n);

    // layer 1: hB = A*hA; out += hB; zero hA
    spmm_atomic<<<gridEW, TB, 0, stream>>>(adj_rows, adj_cols, adj_vals, hA, hB, E);
    acc_kernel<<<gridV, TB, 0, stream>>>((float4*)out, (const float4*)hB, (float4*)hA, total4);

    // layer 2: hA = A*hB; out += hA; zero hB
    spmm_atomic<<<gridEW, TB, 0, stream>>>(adj_rows, adj_cols, adj_vals, hB, hA, E);
    acc_kernel<<<gridV, TB, 0, stream>>>((float4*)out, (const float4*)hA, (float4*)hB, total4);

    // layer 3: hB = A*hA; out = (out + hB) * 0.25
    spmm_atomic<<<gridEW, TB, 0, stream>>>(adj_rows, adj_cols, adj_vals, hA, hB, E);
    final_kernel<<<gridV, TB, 0, stream>>>((float4*)out, (const float4*)hB, total4);
}

// Round 2
// 716.236 us; speedup vs baseline: 7.4395x; 7.4395x over previous
//
#include <hip/hip_runtime.h>

// LightGCN: final = (ego + A·ego + A²·ego + A³·ego) / 4
// Strategy: per-call counting-sort COO -> CSR, then gather SpMM (no f32 atomics),
// with the layer accumulation fused into the gather epilogue.

#define NUM_USERS 100000
#define NUM_ITEMS 200000
#define NN (NUM_USERS + NUM_ITEMS)
#define DIM 64

// ---------------- zero an int array ----------------
__global__ void zero_ints(int* __restrict__ p, int n) {
    int i = blockIdx.x * blockDim.x + threadIdx.x;
    if (i < n) p[i] = 0;
}

// ---------------- histogram of row indices ----------------
__global__ void hist_kernel(const int* __restrict__ rows, int* __restrict__ counts, int E) {
    int e = blockIdx.x * blockDim.x + threadIdx.x;
    if (e < E) atomicAdd(&counts[rows[e]], 1);
}

// ---------------- scan pass 1: per-block (1024 elems) partial sums ----------------
__global__ void scan_partials(const int* __restrict__ counts, int* __restrict__ blocksums, int n) {
    __shared__ int lds[256];
    int tid = threadIdx.x;
    int base = blockIdx.x * 1024 + tid * 4;
    int s = 0;
#pragma unroll
    for (int k = 0; k < 4; ++k) { int idx = base + k; if (idx < n) s += counts[idx]; }
    lds[tid] = s;
    __syncthreads();
    for (int off = 128; off > 0; off >>= 1) {
        if (tid < off) lds[tid] += lds[tid + off];
        __syncthreads();
    }
    if (tid == 0) blocksums[blockIdx.x] = lds[0];
}

// ---------------- scan pass 2: exclusive scan of block sums (single thread) ------
__global__ void scan_blocksums(int* __restrict__ blocksums, int nb, int* __restrict__ row_start, int n) {
    int run = 0;
    for (int b = 0; b < nb; ++b) { int v = blocksums[b]; blocksums[b] = run; run += v; }
    row_start[n] = run;   // = E
}

// ---------------- scan pass 3: block-local exclusive scan + write ----------------
// counts array is rewritten in-place as row_start[0..n); cursor gets a copy.
__global__ void scan_write(int* __restrict__ counts, const int* __restrict__ blocksums,
                           int* __restrict__ cursor, int n) {
    __shared__ int lds[256];
    int tid = threadIdx.x;
    int base = blockIdx.x * 1024 + tid * 4;
    int local[4]; int tsum = 0;
#pragma unroll
    for (int k = 0; k < 4; ++k) {
        int idx = base + k;
        local[k] = (idx < n) ? counts[idx] : 0;
        tsum += local[k];
    }
    lds[tid] = tsum;
    __syncthreads();
    for (int off = 1; off < 256; off <<= 1) {
        int v = 0;
        if (tid >= off) v = lds[tid - off];
        __syncthreads();
        lds[tid] += v;
        __syncthreads();
    }
    int run = lds[tid] - tsum + blocksums[blockIdx.x];   // exclusive prefix for this thread
#pragma unroll
    for (int k = 0; k < 4; ++k) {
        int idx = base + k;
        if (idx < n) { counts[idx] = run; cursor[idx] = run; run += local[k]; }
    }
}

// ---------------- scatter edges into CSR order ----------------
__global__ void scatter_edges(const int* __restrict__ rows, const int* __restrict__ cols,
                              const float* __restrict__ vals, int* __restrict__ cursor,
                              int* __restrict__ scol, float* __restrict__ sval, int E) {
    int e = blockIdx.x * blockDim.x + threadIdx.x;
    if (e >= E) return;
    int r = rows[e];
    int p = atomicAdd(&cursor[r], 1);
    scol[p] = cols[e];
    sval[p] = vals[e];
}

// ---------------- init: out = ego, h0 = ego ----------------
__global__ void init_kernel(const float4* __restrict__ user4,
                            const float4* __restrict__ item4,
                            float4* __restrict__ out4,
                            float4* __restrict__ h4,
                            int total4, int user4n) {
    int i = blockIdx.x * blockDim.x + threadIdx.x;
    if (i >= total4) return;
    float4 v = (i < user4n) ? user4[i] : item4[i - user4n];
    out4[i] = v;
    h4[i]  = v;
}

// ---------------- gather SpMM fused with accumulation ----------------
// 16 lanes per row, float4 per lane. y[row] = sum v*x[col]; out += y (or final avg).
__global__ void spmm_gather(const int* __restrict__ row_start,
                            const int* __restrict__ scol,
                            const float* __restrict__ sval,
                            const float* __restrict__ x,
                            float* __restrict__ y,
                            float* __restrict__ out,
                            int is_final) {
    int tid = threadIdx.x;
    int sub = tid >> 4;
    int lane = tid & 15;
    int row = blockIdx.x * 16 + sub;
    if (row >= NN) return;
    int s = row_start[row];
    int e = row_start[row + 1];
    float4 acc = make_float4(0.f, 0.f, 0.f, 0.f);
    for (int j = s; j < e; ++j) {
        int c = scol[j];
        float v = sval[j];
        const float4 xv = *(const float4*)(x + c * DIM + (lane << 2));
        acc.x += v * xv.x; acc.y += v * xv.y; acc.z += v * xv.z; acc.w += v * xv.w;
    }
    int o = row * DIM + (lane << 2);
    float4 ov = *(const float4*)(out + o);
    if (is_final) {
        ov.x = (ov.x + acc.x) * 0.25f;
        ov.y = (ov.y + acc.y) * 0.25f;
        ov.z = (ov.z + acc.z) * 0.25f;
        ov.w = (ov.w + acc.w) * 0.25f;
        *(float4*)(out + o) = ov;
    } else {
        *(float4*)(y + o) = acc;
        ov.x += acc.x; ov.y += acc.y; ov.z += acc.z; ov.w += acc.w;
        *(float4*)(out + o) = ov;
    }
}

extern "C" void kernel_launch(void* const* d_in, const int* in_sizes, int n_in,
                              void* d_out, int out_size, void* d_ws, size_t ws_size,
                              hipStream_t stream) {
    const float* user_emb = (const float*)d_in[0];
    const float* item_emb = (const float*)d_in[1];
    const int*   adj_rows = (const int*)d_in[2];
    const int*   adj_cols = (const int*)d_in[3];
    const float* adj_vals = (const float*)d_in[4];
    float* out = (float*)d_out;

    const int E = in_sizes[2];
    const int total = NN * DIM;            // 19.2M floats
    const int total4 = total / 4;          // 4.8M
    const int user4n = NUM_USERS * DIM / 4;

    // workspace layout
    float* hA = (float*)d_ws;              // total floats
    float* hB = hA + total;                // total floats
    int*   scol = (int*)(hB + total);      // E ints
    float* sval = (float*)(scol + E);      // E floats
    int*   row_start = (int*)(sval + E);   // NN+1 ints (also the histogram counts)
    int*   cursor = row_start + NN + 1;    // NN+1 ints
    int*   blocksums = cursor + NN + 1;    // scan partials

    const int TB = 256;
    const int gridE = (E + TB - 1) / TB;
    const int gridV = (total4 + TB - 1) / TB;
    const int gridN = (NN + 1 + TB - 1) / TB;
    const int nScan = (NN + 1023) / 1024;            // 293
    const int gridG = (NN + 15) / 16;                // 18750

    // ---- CSR build ----
    zero_ints<<<gridN, TB, 0, stream>>>(row_start, NN + 1);
    hist_kernel<<<gridE, TB, 0, stream>>>(adj_rows, row_start, E);
    scan_partials<<<nScan, TB, 0, stream>>>(row_start, blocksums, NN);
    scan_blocksums<<<1, 1, 0, stream>>>(blocksums, nScan, row_start, NN);
    scan_write<<<nScan, TB, 0, stream>>>(row_start, blocksums, cursor, NN);
    scatter_edges<<<gridE, TB, 0, stream>>>(adj_rows, adj_cols, adj_vals, cursor, scol, sval, E);

    // ---- init acc/out and h0 ----
    init_kernel<<<gridV, TB, 0, stream>>>((const float4*)user_emb, (const float4*)item_emb,
                                          (float4*)out, (float4*)hA, total4, user4n);

    // ---- 3 gather SpMM layers, accumulation fused ----
    spmm_gather<<<gridG, TB, 0, stream>>>(row_start, scol, sval, hA, hB, out, 0); // h1=A*ego
    spmm_gather<<<gridG, TB, 0, stream>>>(row_start, scol, sval, hB, hA, out, 0); // h2=A*h1
    spmm_gather<<<gridG, TB, 0, stream>>>(row_start, scol, sval, hA, hB, out, 1); // h3; out=(out+h3)/4
}

// Round 3
// 635.723 us; speedup vs baseline: 8.3817x; 1.1266x over previous
//
#include <hip/hip_runtime.h>
#include <hip/hip_bf16.h>

// LightGCN: final = (ego + A·ego + A²·ego + A³·ego) / 4
// CSR build per call (counting sort, packed (col,val) float2 edges),
// gather SpMM with bf16 feature storage, f32 accumulation, fused epilogue.

#define NUM_USERS 100000
#define NUM_ITEMS 200000
#define NN (NUM_USERS + NUM_ITEMS)
#define DIM 64

__device__ __forceinline__ float bf16_to_f32(unsigned short u) {
    return __uint_as_float(((unsigned int)u) << 16);
}
__device__ __forceinline__ unsigned short f32_to_bf16(float f) {
    unsigned int u = __float_as_uint(f);
    u += 0x7fffu + ((u >> 16) & 1u);   // round-to-nearest-even
    return (unsigned short)(u >> 16);
}

// ---------------- zero an int array ----------------
__global__ void zero_ints(int* __restrict__ p, int n) {
    int i = blockIdx.x * blockDim.x + threadIdx.x;
    if (i < n) p[i] = 0;
}

// ---------------- histogram of row indices ----------------
__global__ void hist_kernel(const int* __restrict__ rows, int* __restrict__ counts, int E) {
    int e = blockIdx.x * blockDim.x + threadIdx.x;
    if (e < E) atomicAdd(&counts[rows[e]], 1);
}

// ---------------- scan pass 1: per-block (1024 elems) partial sums ----------------
__global__ void scan_partials(const int* __restrict__ counts, int* __restrict__ blocksums, int n) {
    __shared__ int lds[256];
    int tid = threadIdx.x;
    int base = blockIdx.x * 1024 + tid * 4;
    int s = 0;
#pragma unroll
    for (int k = 0; k < 4; ++k) { int idx = base + k; if (idx < n) s += counts[idx]; }
    lds[tid] = s;
    __syncthreads();
    for (int off = 128; off > 0; off >>= 1) {
        if (tid < off) lds[tid] += lds[tid + off];
        __syncthreads();
    }
    if (tid == 0) blocksums[blockIdx.x] = lds[0];
}

// ---------------- scan pass 2: exclusive scan of block sums (one block) ----------
__global__ void scan_blocksums_par(int* __restrict__ blocksums, int nb,
                                   int* __restrict__ row_start, int n) {
    __shared__ int lds[512];
    int t = threadIdx.x;
    int v = (t < nb) ? blocksums[t] : 0;
    lds[t] = v;
    __syncthreads();
    for (int off = 1; off < 512; off <<= 1) {
        int u = (t >= off) ? lds[t - off] : 0;
        __syncthreads();
        lds[t] += u;
        __syncthreads();
    }
    if (t < nb) blocksums[t] = lds[t] - v;     // exclusive
    if (t == 0) row_start[n] = lds[nb - 1];    // total = E
}

// ---------------- scan pass 3: block-local exclusive scan + write ----------------
__global__ void scan_write(int* __restrict__ counts, const int* __restrict__ blocksums,
                           int* __restrict__ cursor, int n) {
    __shared__ int lds[256];
    int tid = threadIdx.x;
    int base = blockIdx.x * 1024 + tid * 4;
    int local[4]; int tsum = 0;
#pragma unroll
    for (int k = 0; k < 4; ++k) {
        int idx = base + k;
        local[k] = (idx < n) ? counts[idx] : 0;
        tsum += local[k];
    }
    lds[tid] = tsum;
    __syncthreads();
    for (int off = 1; off < 256; off <<= 1) {
        int v = 0;
        if (tid >= off) v = lds[tid - off];
        __syncthreads();
        lds[tid] += v;
        __syncthreads();
    }
    int run = lds[tid] - tsum + blocksums[blockIdx.x];
#pragma unroll
    for (int k = 0; k < 4; ++k) {
        int idx = base + k;
        if (idx < n) { counts[idx] = run; cursor[idx] = run; run += local[k]; }
    }
}

// ---------------- scatter edges into CSR order, packed (col,val) ----------------
__global__ void scatter_edges(const int* __restrict__ rows, const int* __restrict__ cols,
                              const float* __restrict__ vals, int* __restrict__ cursor,
                              float2* __restrict__ epack, int E) {
    int e = blockIdx.x * blockDim.x + threadIdx.x;
    if (e >= E) return;
    int r = rows[e];
    int p = atomicAdd(&cursor[r], 1);
    epack[p] = make_float2(__int_as_float(cols[e]), vals[e]);
}

// ---------------- init: out = ego (f32), h0 = ego (bf16) ----------------
__global__ void init_kernel(const float4* __restrict__ user4,
                            const float4* __restrict__ item4,
                            float4* __restrict__ out4,
                            ushort4* __restrict__ h4,
                            int total4, int user4n) {
    int i = blockIdx.x * blockDim.x + threadIdx.x;
    if (i >= total4) return;
    float4 v = (i < user4n) ? user4[i] : item4[i - user4n];
    out4[i] = v;
    ushort4 b;
    b.x = f32_to_bf16(v.x); b.y = f32_to_bf16(v.y);
    b.z = f32_to_bf16(v.z); b.w = f32_to_bf16(v.w);
    h4[i] = b;
}

// ---------------- gather SpMM fused with accumulation ----------------
// 16 lanes per row, 4 bf16 per lane. y[row] = sum v*x[col]; out += y (or final avg).
__global__ void spmm_gather(const int* __restrict__ row_start,
                            const float2* __restrict__ epack,
                            const unsigned short* __restrict__ x,   // bf16 bits
                            unsigned short* __restrict__ y,         // bf16 bits
                            float* __restrict__ out,
                            int is_final) {
    int tid = threadIdx.x;
    int sub = tid >> 4;
    int lane = tid & 15;
    int row = blockIdx.x * 16 + sub;
    if (row >= NN) return;
    int s = row_start[row];
    int e = row_start[row + 1];
    float ax = 0.f, ay = 0.f, az = 0.f, aw = 0.f;
    for (int j = s; j < e; ++j) {
        float2 ev = epack[j];                 // same addr across 16 lanes -> broadcast
        int c = __float_as_int(ev.x);
        float v = ev.y;
        const ushort4 xb = *(const ushort4*)(x + c * DIM + (lane << 2));
        ax += v * bf16_to_f32(xb.x);
        ay += v * bf16_to_f32(xb.y);
        az += v * bf16_to_f32(xb.z);
        aw += v * bf16_to_f32(xb.w);
    }
    int o = row * DIM + (lane << 2);
    float4 ov = *(const float4*)(out + o);
    if (is_final) {
        ov.x = (ov.x + ax) * 0.25f;
        ov.y = (ov.y + ay) * 0.25f;
        ov.z = (ov.z + az) * 0.25f;
        ov.w = (ov.w + aw) * 0.25f;
        *(float4*)(out + o) = ov;
    } else {
        ushort4 yb;
        yb.x = f32_to_bf16(ax); yb.y = f32_to_bf16(ay);
        yb.z = f32_to_bf16(az); yb.w = f32_to_bf16(aw);
        *(ushort4*)(y + o) = yb;
        ov.x += ax; ov.y += ay; ov.z += az; ov.w += aw;
        *(float4*)(out + o) = ov;
    }
}

extern "C" void kernel_launch(void* const* d_in, const int* in_sizes, int n_in,
                              void* d_out, int out_size, void* d_ws, size_t ws_size,
                              hipStream_t stream) {
    const float* user_emb = (const float*)d_in[0];
    const float* item_emb = (const float*)d_in[1];
    const int*   adj_rows = (const int*)d_in[2];
    const int*   adj_cols = (const int*)d_in[3];
    const float* adj_vals = (const float*)d_in[4];
    float* out = (float*)d_out;

    const int E = in_sizes[2];
    const int total = NN * DIM;            // 19.2M elems
    const int total4 = total / 4;          // 4.8M
    const int user4n = NUM_USERS * DIM / 4;

    // workspace layout (8B-aligned first)
    float2* epack = (float2*)d_ws;                         // E float2 (16 MB)
    unsigned short* hA = (unsigned short*)(epack + E);     // total bf16
    unsigned short* hB = hA + total;                       // total bf16
    int* row_start = (int*)(hB + total);                   // NN+1 ints
    int* cursor    = row_start + NN + 1;                   // NN+1 ints
    int* blocksums = cursor + NN + 1;                      // scan partials

    const int TB = 256;
    const int gridE = (E + TB - 1) / TB;
    const int gridV = (total4 + TB - 1) / TB;
    const int gridN = (NN + 1 + TB - 1) / TB;
    const int nScan = (NN + 1023) / 1024;            // 293
    const int gridG = (NN + 15) / 16;                // 18750

    // ---- CSR build ----
    zero_ints<<<gridN, TB, 0, stream>>>(row_start, NN + 1);
    hist_kernel<<<gridE, TB, 0, stream>>>(adj_rows, row_start, E);
    scan_partials<<<nScan, TB, 0, stream>>>(row_start, blocksums, NN);
    scan_blocksums_par<<<1, 512, 0, stream>>>(blocksums, nScan, row_start, NN);
    scan_write<<<nScan, TB, 0, stream>>>(row_start, blocksums, cursor, NN);
    scatter_edges<<<gridE, TB, 0, stream>>>(adj_rows, adj_cols, adj_vals, cursor, epack, E);

    // ---- init acc/out and h0 ----
    init_kernel<<<gridV, TB, 0, stream>>>((const float4*)user_emb, (const float4*)item_emb,
                                          (float4*)out, (ushort4*)hA, total4, user4n);

    // ---- 3 gather SpMM layers, accumulation fused ----
    spmm_gather<<<gridG, TB, 0, stream>>>(row_start, epack, hA, hB, out, 0); // h1
    spmm_gather<<<gridG, TB, 0, stream>>>(row_start, epack, hB, hA, out, 0); // h2
    spmm_gather<<<gridG, TB, 0, stream>>>(row_start, epack, hA, hB, out, 1); // h3 + avg
}

// Round 4
// 616.520 us; speedup vs baseline: 8.6428x; 1.0311x over previous
//
#include <hip/hip_runtime.h>
#include <hip/hip_bf16.h>

// LightGCN: final = (ego + A·ego + A²·ego + A³·ego) / 4
// CSR build per call: histogram + scan + XCD-partitioned counting-sort scatter
// (packed (col,val) float2). Gather SpMM with bf16 feature storage, f32 acc,
// final combine kernel reads ego + h1..h3 once.

#define NUM_USERS 100000
#define NUM_ITEMS 200000
#define NN (NUM_USERS + NUM_ITEMS)
#define DIM 64
#define NPART 16
#define PART_ROWS (NN / NPART)   // 18750

__device__ __forceinline__ float bf16_to_f32(unsigned short u) {
    return __uint_as_float(((unsigned int)u) << 16);
}
__device__ __forceinline__ unsigned short f32_to_bf16(float f) {
    unsigned int u = __float_as_uint(f);
    u += 0x7fffu + ((u >> 16) & 1u);   // round-to-nearest-even
    return (unsigned short)(u >> 16);
}

// ---------------- zero an int array ----------------
__global__ void zero_ints(int* __restrict__ p, int n) {
    int i = blockIdx.x * blockDim.x + threadIdx.x;
    if (i < n) p[i] = 0;
}

// ---------------- histogram of row indices ----------------
__global__ void hist_kernel(const int* __restrict__ rows, int* __restrict__ counts, int E) {
    int e = blockIdx.x * blockDim.x + threadIdx.x;
    if (e < E) atomicAdd(&counts[rows[e]], 1);
}

// ---------------- scan pass 1: per-block (1024 elems) partial sums ----------------
__global__ void scan_partials(const int* __restrict__ counts, int* __restrict__ blocksums, int n) {
    __shared__ int lds[256];
    int tid = threadIdx.x;
    int base = blockIdx.x * 1024 + tid * 4;
    int s = 0;
#pragma unroll
    for (int k = 0; k < 4; ++k) { int idx = base + k; if (idx < n) s += counts[idx]; }
    lds[tid] = s;
    __syncthreads();
    for (int off = 128; off > 0; off >>= 1) {
        if (tid < off) lds[tid] += lds[tid + off];
        __syncthreads();
    }
    if (tid == 0) blocksums[blockIdx.x] = lds[0];
}

// ---------------- scan pass 2: exclusive scan of block sums (one block) ----------
__global__ void scan_blocksums_par(int* __restrict__ blocksums, int nb,
                                   int* __restrict__ row_start, int n) {
    __shared__ int lds[512];
    int t = threadIdx.x;
    int v = (t < nb) ? blocksums[t] : 0;
    lds[t] = v;
    __syncthreads();
    for (int off = 1; off < 512; off <<= 1) {
        int u = (t >= off) ? lds[t - off] : 0;
        __syncthreads();
        lds[t] += u;
        __syncthreads();
    }
    if (t < nb) blocksums[t] = lds[t] - v;     // exclusive
    if (t == 0) row_start[n] = lds[nb - 1];    // total = E
}

// ---------------- scan pass 3: block-local exclusive scan + write ----------------
__global__ void scan_write(int* __restrict__ counts, const int* __restrict__ blocksums,
                           int* __restrict__ cursor, int n) {
    __shared__ int lds[256];
    int tid = threadIdx.x;
    int base = blockIdx.x * 1024 + tid * 4;
    int local[4]; int tsum = 0;
#pragma unroll
    for (int k = 0; k < 4; ++k) {
        int idx = base + k;
        local[k] = (idx < n) ? counts[idx] : 0;
        tsum += local[k];
    }
    lds[tid] = tsum;
    __syncthreads();
    for (int off = 1; off < 256; off <<= 1) {
        int v = 0;
        if (tid >= off) v = lds[tid - off];
        __syncthreads();
        lds[tid] += v;
        __syncthreads();
    }
    int run = lds[tid] - tsum + blocksums[blockIdx.x];
#pragma unroll
    for (int k = 0; k < 4; ++k) {
        int idx = base + k;
        if (idx < n) { counts[idx] = run; cursor[idx] = run; run += local[k]; }
    }
}

// ---------------- XCD-partitioned scatter into CSR order ----------------
// partition = blockIdx & 15 -> runs on XCD (blockIdx & 7) under round-robin
// dispatch, so each XCD's dirty destination region (~2 MB) stays L2-resident
// and scatter lines merge fully before writeback.
__global__ void scatter_part(const int* __restrict__ rows, const int* __restrict__ cols,
                             const float* __restrict__ vals, int* __restrict__ cursor,
                             float2* __restrict__ epack, int E) {
    int part = blockIdx.x & (NPART - 1);
    int chunk = blockIdx.x >> 4;
    int base = chunk * 1024 + threadIdx.x * 4;   // 4 edges per thread
    if (base >= E) return;
    unsigned int lo = (unsigned int)(part * PART_ROWS);
    if (base + 3 < E) {
        int4 r4 = *(const int4*)(rows + base);
        int rr[4] = { r4.x, r4.y, r4.z, r4.w };
#pragma unroll
        for (int k = 0; k < 4; ++k) {
            int r = rr[k];
            if ((unsigned int)(r - lo) < (unsigned int)PART_ROWS) {
                int e = base + k;
                int p = atomicAdd(&cursor[r], 1);
                epack[p] = make_float2(__int_as_float(cols[e]), vals[e]);
            }
        }
    } else {
        for (int k = 0; k < 4; ++k) {
            int e = base + k;
            if (e >= E) break;
            int r = rows[e];
            if ((unsigned int)(r - lo) < (unsigned int)PART_ROWS) {
                int p = atomicAdd(&cursor[r], 1);
                epack[p] = make_float2(__int_as_float(cols[e]), vals[e]);
            }
        }
    }
}

// ---------------- init: h0 = ego (bf16) ----------------
__global__ void init_h0(const float4* __restrict__ user4,
                        const float4* __restrict__ item4,
                        ushort4* __restrict__ h4,
                        int total4, int user4n) {
    int i = blockIdx.x * blockDim.x + threadIdx.x;
    if (i >= total4) return;
    float4 v = (i < user4n) ? user4[i] : item4[i - user4n];
    ushort4 b;
    b.x = f32_to_bf16(v.x); b.y = f32_to_bf16(v.y);
    b.z = f32_to_bf16(v.z); b.w = f32_to_bf16(v.w);
    h4[i] = b;
}

// ---------------- gather SpMM: y = A * x (bf16 in/out, f32 acc) --------------
__global__ void spmm_gather(const int* __restrict__ row_start,
                            const float2* __restrict__ epack,
                            const unsigned short* __restrict__ x,
                            unsigned short* __restrict__ y) {
    int tid = threadIdx.x;
    int sub = tid >> 4;
    int lane = tid & 15;
    int row = blockIdx.x * 16 + sub;
    if (row >= NN) return;
    int s = row_start[row];
    int e = row_start[row + 1];
    float ax = 0.f, ay = 0.f, az = 0.f, aw = 0.f;
    for (int j = s; j < e; ++j) {
        float2 ev = epack[j];                 // same addr across 16 lanes -> broadcast
        int c = __float_as_int(ev.x);
        float v = ev.y;
        const ushort4 xb = *(const ushort4*)(x + c * DIM + (lane << 2));
        ax += v * bf16_to_f32(xb.x);
        ay += v * bf16_to_f32(xb.y);
        az += v * bf16_to_f32(xb.z);
        aw += v * bf16_to_f32(xb.w);
    }
    ushort4 yb;
    yb.x = f32_to_bf16(ax); yb.y = f32_to_bf16(ay);
    yb.z = f32_to_bf16(az); yb.w = f32_to_bf16(aw);
    *(ushort4*)(y + row * DIM + (lane << 2)) = yb;
}

// ---------------- final: out = (ego + h1 + h2 + h3) * 0.25 ----------------
__global__ void final_combine(const float4* __restrict__ user4,
                              const float4* __restrict__ item4,
                              const ushort4* __restrict__ h1,
                              const ushort4* __restrict__ h2,
                              const ushort4* __restrict__ h3,
                              float4* __restrict__ out4,
                              int total4, int user4n) {
    int i = blockIdx.x * blockDim.x + threadIdx.x;
    if (i >= total4) return;
    float4 ego = (i < user4n) ? user4[i] : item4[i - user4n];
    ushort4 a = h1[i], b = h2[i], c = h3[i];
    float4 o;
    o.x = (ego.x + bf16_to_f32(a.x) + bf16_to_f32(b.x) + bf16_to_f32(c.x)) * 0.25f;
    o.y = (ego.y + bf16_to_f32(a.y) + bf16_to_f32(b.y) + bf16_to_f32(c.y)) * 0.25f;
    o.z = (ego.z + bf16_to_f32(a.z) + bf16_to_f32(b.z) + bf16_to_f32(c.z)) * 0.25f;
    o.w = (ego.w + bf16_to_f32(a.w) + bf16_to_f32(b.w) + bf16_to_f32(c.w)) * 0.25f;
    out4[i] = o;
}

extern "C" void kernel_launch(void* const* d_in, const int* in_sizes, int n_in,
                              void* d_out, int out_size, void* d_ws, size_t ws_size,
                              hipStream_t stream) {
    const float* user_emb = (const float*)d_in[0];
    const float* item_emb = (const float*)d_in[1];
    const int*   adj_rows = (const int*)d_in[2];
    const int*   adj_cols = (const int*)d_in[3];
    const float* adj_vals = (const float*)d_in[4];
    float* out = (float*)d_out;

    const int E = in_sizes[2];
    const int total = NN * DIM;            // 19.2M elems
    const int total4 = total / 4;          // 4.8M
    const int user4n = NUM_USERS * DIM / 4;

    // workspace layout (8B-aligned first)
    float2* epack = (float2*)d_ws;                         // E float2 (16 MB)
    unsigned short* hA = (unsigned short*)(epack + E);     // total bf16 (h0, then h3)
    unsigned short* hB = hA + total;                       // total bf16 (h1)
    unsigned short* hC = hB + total;                       // total bf16 (h2)
    int* row_start = (int*)(hC + total);                   // NN+1 ints
    int* cursor    = row_start + NN + 1;                   // NN+1 ints
    int* blocksums = cursor + NN + 1;                      // scan partials

    const int TB = 256;
    const int gridE = (E + TB - 1) / TB;
    const int gridV = (total4 + TB - 1) / TB;
    const int gridN = (NN + 1 + TB - 1) / TB;
    const int nScan = (NN + 1023) / 1024;            // 293
    const int gridG = (NN + 15) / 16;                // 18750
    const int nChunks = (E + 1023) / 1024;
    const int gridS = nChunks * NPART;

    // ---- CSR build ----
    zero_ints<<<gridN, TB, 0, stream>>>(row_start, NN + 1);
    hist_kernel<<<gridE, TB, 0, stream>>>(adj_rows, row_start, E);
    scan_partials<<<nScan, TB, 0, stream>>>(row_start, blocksums, NN);
    scan_blocksums_par<<<1, 512, 0, stream>>>(blocksums, nScan, row_start, NN);
    scan_write<<<nScan, TB, 0, stream>>>(row_start, blocksums, cursor, NN);
    scatter_part<<<gridS, TB, 0, stream>>>(adj_rows, adj_cols, adj_vals, cursor, epack, E);

    // ---- init h0 ----
    init_h0<<<gridV, TB, 0, stream>>>((const float4*)user_emb, (const float4*)item_emb,
                                      (ushort4*)hA, total4, user4n);

    // ---- 3 gather SpMM layers ----
    spmm_gather<<<gridG, TB, 0, stream>>>(row_start, epack, hA, hB); // h1 = A*h0
    spmm_gather<<<gridG, TB, 0, stream>>>(row_start, epack, hB, hC); // h2 = A*h1
    spmm_gather<<<gridG, TB, 0, stream>>>(row_start, epack, hC, hA); // h3 = A*h2

    // ---- final combine ----
    final_combine<<<gridV, TB, 0, stream>>>((const float4*)user_emb, (const float4*)item_emb,
                                            (const ushort4*)hB, (const ushort4*)hC,
                                            (const ushort4*)hA, (float4*)out,
                                            total4, user4n);
}

// Round 5
// 516.066 us; speedup vs baseline: 10.3252x; 1.1947x over previous
//
#include <hip/hip_runtime.h>
#include <hip/hip_bf16.h>

// LightGCN: final = (ego + A·ego + A²·ego + A³·ego) / 4
// CSR build per call (hist + scan + XCD-partitioned counting-sort scatter,
// packed (col,val) float2). Gather SpMM: bf16 features, 8 lanes/row (16B loads),
// unroll-2 dual-accumulator for MLP. Final combine reads ego + h1..h3 once.

#define NUM_USERS 100000
#define NUM_ITEMS 200000
#define NN (NUM_USERS + NUM_ITEMS)
#define DIM 64
#define NPART 8
#define PART_ROWS (NN / NPART)   // 37500

typedef unsigned short ushort8_t __attribute__((ext_vector_type(8)));

__device__ __forceinline__ float bf16_to_f32(unsigned short u) {
    return __uint_as_float(((unsigned int)u) << 16);
}
__device__ __forceinline__ unsigned short f32_to_bf16(float f) {
    unsigned int u = __float_as_uint(f);
    u += 0x7fffu + ((u >> 16) & 1u);   // round-to-nearest-even
    return (unsigned short)(u >> 16);
}

// ---------------- zero an int array ----------------
__global__ void zero_ints(int* __restrict__ p, int n) {
    int i = blockIdx.x * blockDim.x + threadIdx.x;
    if (i < n) p[i] = 0;
}

// ---------------- histogram of row indices ----------------
__global__ void hist_kernel(const int* __restrict__ rows, int* __restrict__ counts, int E) {
    int e = blockIdx.x * blockDim.x + threadIdx.x;
    if (e < E) atomicAdd(&counts[rows[e]], 1);
}

// ---------------- scan pass 1: per-block (1024 elems) partial sums ----------------
__global__ void scan_partials(const int* __restrict__ counts, int* __restrict__ blocksums, int n) {
    __shared__ int lds[256];
    int tid = threadIdx.x;
    int base = blockIdx.x * 1024 + tid * 4;
    int s = 0;
#pragma unroll
    for (int k = 0; k < 4; ++k) { int idx = base + k; if (idx < n) s += counts[idx]; }
    lds[tid] = s;
    __syncthreads();
    for (int off = 128; off > 0; off >>= 1) {
        if (tid < off) lds[tid] += lds[tid + off];
        __syncthreads();
    }
    if (tid == 0) blocksums[blockIdx.x] = lds[0];
}

// ---------------- scan pass 2: exclusive scan of block sums (one block) ----------
__global__ void scan_blocksums_par(int* __restrict__ blocksums, int nb,
                                   int* __restrict__ row_start, int n) {
    __shared__ int lds[512];
    int t = threadIdx.x;
    int v = (t < nb) ? blocksums[t] : 0;
    lds[t] = v;
    __syncthreads();
    for (int off = 1; off < 512; off <<= 1) {
        int u = (t >= off) ? lds[t - off] : 0;
        __syncthreads();
        lds[t] += u;
        __syncthreads();
    }
    if (t < nb) blocksums[t] = lds[t] - v;     // exclusive
    if (t == 0) row_start[n] = lds[nb - 1];    // total = E
}

// ---------------- scan pass 3: block-local exclusive scan + write ----------------
__global__ void scan_write(int* __restrict__ counts, const int* __restrict__ blocksums,
                           int* __restrict__ cursor, int n) {
    __shared__ int lds[256];
    int tid = threadIdx.x;
    int base = blockIdx.x * 1024 + tid * 4;
    int local[4]; int tsum = 0;
#pragma unroll
    for (int k = 0; k < 4; ++k) {
        int idx = base + k;
        local[k] = (idx < n) ? counts[idx] : 0;
        tsum += local[k];
    }
    lds[tid] = tsum;
    __syncthreads();
    for (int off = 1; off < 256; off <<= 1) {
        int v = 0;
        if (tid >= off) v = lds[tid - off];
        __syncthreads();
        lds[tid] += v;
        __syncthreads();
    }
    int run = lds[tid] - tsum + blocksums[blockIdx.x];
#pragma unroll
    for (int k = 0; k < 4; ++k) {
        int idx = base + k;
        if (idx < n) { counts[idx] = run; cursor[idx] = run; run += local[k]; }
    }
}

// ---------------- XCD-partitioned scatter into CSR order ----------------
// partition = blockIdx & 7 -> XCD (blockIdx & 7) under round-robin dispatch.
__global__ void scatter_part(const int* __restrict__ rows, const int* __restrict__ cols,
                             const float* __restrict__ vals, int* __restrict__ cursor,
                             float2* __restrict__ epack, int E) {
    int part = blockIdx.x & (NPART - 1);
    int chunk = blockIdx.x >> 3;
    int base = chunk * 1024 + threadIdx.x * 4;   // 4 edges per thread
    if (base >= E) return;
    unsigned int lo = (unsigned int)(part * PART_ROWS);
    if (base + 3 < E) {
        int4 r4 = *(const int4*)(rows + base);
        int rr[4] = { r4.x, r4.y, r4.z, r4.w };
#pragma unroll
        for (int k = 0; k < 4; ++k) {
            int r = rr[k];
            if ((unsigned int)(r - lo) < (unsigned int)PART_ROWS) {
                int e = base + k;
                int p = atomicAdd(&cursor[r], 1);
                epack[p] = make_float2(__int_as_float(cols[e]), vals[e]);
            }
        }
    } else {
        for (int k = 0; k < 4; ++k) {
            int e = base + k;
            if (e >= E) break;
            int r = rows[e];
            if ((unsigned int)(r - lo) < (unsigned int)PART_ROWS) {
                int p = atomicAdd(&cursor[r], 1);
                epack[p] = make_float2(__int_as_float(cols[e]), vals[e]);
            }
        }
    }
}

// ---------------- init: h0 = ego (bf16) ----------------
__global__ void init_h0(const float4* __restrict__ user4,
                        const float4* __restrict__ item4,
                        ushort4* __restrict__ h4,
                        int total4, int user4n) {
    int i = blockIdx.x * blockDim.x + threadIdx.x;
    if (i >= total4) return;
    float4 v = (i < user4n) ? user4[i] : item4[i - user4n];
    ushort4 b;
    b.x = f32_to_bf16(v.x); b.y = f32_to_bf16(v.y);
    b.z = f32_to_bf16(v.z); b.w = f32_to_bf16(v.w);
    h4[i] = b;
}

// ---------------- gather SpMM: y = A * x (bf16 in/out, f32 acc) --------------
// 8 lanes/row, 16B ushort8 loads, unroll-2 with dual accumulators.
__global__ void spmm_gather(const int* __restrict__ row_start,
                            const float2* __restrict__ epack,
                            const unsigned short* __restrict__ x,
                            unsigned short* __restrict__ y) {
    int tid = threadIdx.x;
    int sub = tid >> 3;          // 0..31 rows per block
    int lane = tid & 7;          // 8 lanes per row, 8 bf16 each
    int row = blockIdx.x * 32 + sub;
    if (row >= NN) return;
    int s = row_start[row];
    int e = row_start[row + 1];
    int off = lane << 3;         // element offset within row

    float a0[8], a1[8];
#pragma unroll
    for (int k = 0; k < 8; ++k) { a0[k] = 0.f; a1[k] = 0.f; }

    int j = s;
    for (; j + 1 < e; j += 2) {
        float2 e0 = epack[j];
        float2 e1 = epack[j + 1];
        int c0 = __float_as_int(e0.x);
        int c1 = __float_as_int(e1.x);
        ushort8_t x0 = *(const ushort8_t*)(x + c0 * DIM + off);
        ushort8_t x1 = *(const ushort8_t*)(x + c1 * DIM + off);
        float v0 = e0.y, v1 = e1.y;
#pragma unroll
        for (int k = 0; k < 8; ++k) a0[k] += v0 * bf16_to_f32(x0[k]);
#pragma unroll
        for (int k = 0; k < 8; ++k) a1[k] += v1 * bf16_to_f32(x1[k]);
    }
    if (j < e) {
        float2 e0 = epack[j];
        int c0 = __float_as_int(e0.x);
        ushort8_t x0 = *(const ushort8_t*)(x + c0 * DIM + off);
        float v0 = e0.y;
#pragma unroll
        for (int k = 0; k < 8; ++k) a0[k] += v0 * bf16_to_f32(x0[k]);
    }

    ushort8_t yb;
#pragma unroll
    for (int k = 0; k < 8; ++k) yb[k] = f32_to_bf16(a0[k] + a1[k]);
    *(ushort8_t*)(y + row * DIM + off) = yb;
}

// ---------------- final: out = (ego + h1 + h2 + h3) * 0.25 ----------------
__global__ void final_combine(const float4* __restrict__ user4,
                              const float4* __restrict__ item4,
                              const ushort4* __restrict__ h1,
                              const ushort4* __restrict__ h2,
                              const ushort4* __restrict__ h3,
                              float4* __restrict__ out4,
                              int total4, int user4n) {
    int i = blockIdx.x * blockDim.x + threadIdx.x;
    if (i >= total4) return;
    float4 ego = (i < user4n) ? user4[i] : item4[i - user4n];
    ushort4 a = h1[i], b = h2[i], c = h3[i];
    float4 o;
    o.x = (ego.x + bf16_to_f32(a.x) + bf16_to_f32(b.x) + bf16_to_f32(c.x)) * 0.25f;
    o.y = (ego.y + bf16_to_f32(a.y) + bf16_to_f32(b.y) + bf16_to_f32(c.y)) * 0.25f;
    o.z = (ego.z + bf16_to_f32(a.z) + bf16_to_f32(b.z) + bf16_to_f32(c.z)) * 0.25f;
    o.w = (ego.w + bf16_to_f32(a.w) + bf16_to_f32(b.w) + bf16_to_f32(c.w)) * 0.25f;
    out4[i] = o;
}

extern "C" void kernel_launch(void* const* d_in, const int* in_sizes, int n_in,
                              void* d_out, int out_size, void* d_ws, size_t ws_size,
                              hipStream_t stream) {
    const float* user_emb = (const float*)d_in[0];
    const float* item_emb = (const float*)d_in[1];
    const int*   adj_rows = (const int*)d_in[2];
    const int*   adj_cols = (const int*)d_in[3];
    const float* adj_vals = (const float*)d_in[4];
    float* out = (float*)d_out;

    const int E = in_sizes[2];
    const int total = NN * DIM;            // 19.2M elems
    const int total4 = total / 4;          // 4.8M
    const int user4n = NUM_USERS * DIM / 4;

    // workspace layout (8B-aligned first)
    float2* epack = (float2*)d_ws;                         // E float2 (16 MB)
    unsigned short* hA = (unsigned short*)(epack + E);     // total bf16 (h0, then h3)
    unsigned short* hB = hA + total;                       // total bf16 (h1)
    unsigned short* hC = hB + total;                       // total bf16 (h2)
    int* row_start = (int*)(hC + total);                   // NN+1 ints
    int* cursor    = row_start + NN + 1;                   // NN+1 ints
    int* blocksums = cursor + NN + 1;                      // scan partials

    const int TB = 256;
    const int gridE = (E + TB - 1) / TB;
    const int gridV = (total4 + TB - 1) / TB;
    const int gridN = (NN + 1 + TB - 1) / TB;
    const int nScan = (NN + 1023) / 1024;            // 293
    const int gridG = (NN + 31) / 32;                // 9375
    const int nChunks = (E + 1023) / 1024;
    const int gridS = nChunks * NPART;

    // ---- CSR build ----
    zero_ints<<<gridN, TB, 0, stream>>>(row_start, NN + 1);
    hist_kernel<<<gridE, TB, 0, stream>>>(adj_rows, row_start, E);
    scan_partials<<<nScan, TB, 0, stream>>>(row_start, blocksums, NN);
    scan_blocksums_par<<<1, 512, 0, stream>>>(blocksums, nScan, row_start, NN);
    scan_write<<<nScan, TB, 0, stream>>>(row_start, blocksums, cursor, NN);
    scatter_part<<<gridS, TB, 0, stream>>>(adj_rows, adj_cols, adj_vals, cursor, epack, E);

    // ---- init h0 ----
    init_h0<<<gridV, TB, 0, stream>>>((const float4*)user_emb, (const float4*)item_emb,
                                      (ushort4*)hA, total4, user4n);

    // ---- 3 gather SpMM layers ----
    spmm_gather<<<gridG, TB, 0, stream>>>(row_start, epack, hA, hB); // h1 = A*h0
    spmm_gather<<<gridG, TB, 0, stream>>>(row_start, epack, hB, hC); // h2 = A*h1
    spmm_gather<<<gridG, TB, 0, stream>>>(row_start, epack, hC, hA); // h3 = A*h2

    // ---- final combine ----
    final_combine<<<gridV, TB, 0, stream>>>((const float4*)user_emb, (const float4*)item_emb,
                                            (const ushort4*)hB, (const ushort4*)hC,
                                            (const ushort4*)hA, (float4*)out,
                                            total4, user4n);
}